// Round 12
// baseline (872.994 us; speedup 1.0000x reference)
//
#include <hip/hip_runtime.h>
#include <stdint.h>

// Problem constants: V=32000, B=64, T=256, D=512, H=1024
typedef unsigned short u16;
typedef unsigned int u32;
typedef __attribute__((ext_vector_type(4))) unsigned int u32x4;
typedef __attribute__((ext_vector_type(4))) float f32x4;
typedef __attribute__((ext_vector_type(8))) __bf16 bf16x8;

#define MFMA16(a, b, c) __builtin_amdgcn_mfma_f32_16x16x32_bf16((a), (b), (c), 0, 0, 0)

__device__ __forceinline__ u16 f2b(float f) {
  union { float f; unsigned u; } v; v.f = f;
  unsigned r = v.u + 0x7FFFu + ((v.u >> 16) & 1u);
  return (u16)(r >> 16);
}
__device__ __forceinline__ float b2f(u16 h) {
  union { unsigned u; float f; } v; v.u = ((unsigned)h) << 16;
  return v.f;
}
__device__ __forceinline__ float sigm(float x) { return 1.0f / (1.0f + __expf(-x)); }
__device__ __forceinline__ float tanh_fast(float x) {
  x = fminf(fmaxf(x, -15.0f), 15.0f);
  float t = __expf(2.0f * x);
  return (t - 1.0f) / (t + 1.0f);
}

// ---- LLC write-through / bypass helpers ----
template <int OFF>
__device__ __forceinline__ u32x4 ld16_sc(const void* p) {
  u32x4 r;
  asm volatile("global_load_dwordx4 %0, %1, off offset:%2 sc0 sc1"
               : "=v"(r) : "v"(p), "i"(OFF));
  return r;
}
__device__ __forceinline__ void st16_sc(void* p, u32x4 v) {
  asm volatile("global_store_dwordx4 %0, %1, off sc0 sc1"
               :: "v"(p), "v"(v) : "memory");
}

// async global->LDS, 16B per lane (dst must be wave-uniform base + lane*16)
__device__ __forceinline__ void gld_lds16(const void* g, void* l) {
  __builtin_amdgcn_global_load_lds(
      (const __attribute__((address_space(1))) void*)(g),
      (__attribute__((address_space(3))) void*)(l), 16, 0, 0);
}

// ---------------- fused prep kernel (one launch) ----------------
// blocks [0,1536): Wx^T; [1536,4608): Wh^T; [4608,5120): Wout^T;
// [5120,13312): emb gather+cast; [13312,13568): h0 -> blocked slot 0 (with
// fresh-bits); [13568,21760): zero hbuf slots 1..256 (fresh-bits cleared).
__global__ __launch_bounds__(256) void prep_all(
    const float* __restrict__ Wx, const float* __restrict__ Wh,
    const float* __restrict__ Wout, const int* __restrict__ y,
    const float* __restrict__ emb, const float* __restrict__ hidden,
    u16* __restrict__ wx_t, u16* __restrict__ wh_t, u16* __restrict__ wo_t,
    u16* __restrict__ aemb, u16* __restrict__ hbuf) {
  __shared__ float tile[32][33];
  const int b = blockIdx.x, tid = threadIdx.x;
  const int tx = tid & 31, ty = tid >> 5;

  const float* src = nullptr; u16* dst = nullptr; int R = 0, C = 0, tb = 0;
  if (b < 1536)      { src = Wx;   dst = wx_t; R = 512;  C = 3072; tb = b; }
  else if (b < 4608) { src = Wh;   dst = wh_t; R = 1024; C = 3072; tb = b - 1536; }
  else if (b < 5120) { src = Wout; dst = wo_t; R = 1024; C = 512;  tb = b - 4608; }

  if (src) {  // 32x32 transpose-cast tile
    const int xt = C >> 5;
    const int c0 = (tb % xt) * 32, r0 = (tb / xt) * 32;
    for (int i = ty; i < 32; i += 8)
      tile[i][tx] = src[(size_t)(r0 + i) * C + (c0 + tx)];
    __syncthreads();
    for (int i = ty; i < 32; i += 8)
      dst[(size_t)(c0 + i) * R + (r0 + tx)] = f2b(tile[tx][i]);
    return;
  }
  if (b < 13312) {  // gather: A_emb[m][:] = bf16(emb[y[m]][:])
    const int idx = (b - 5120) * 256 + tid;
    const int m = idx >> 7, d0 = (idx & 127) << 2;
    const float4 v = *reinterpret_cast<const float4*>(emb + (size_t)y[m] * 512 + d0);
    ushort4 o;
    o.x = f2b(v.x); o.y = f2b(v.y); o.z = f2b(v.z); o.w = f2b(v.w);
    *reinterpret_cast<ushort4*>(aemb + (size_t)m * 512 + d0) = o;
    return;
  }
  if (b < 13568) {  // h0 f32 -> blocked bf16 slot 0, even cols carry fresh bit
    const int i = (b - 13312) * 256 + tid;
    const int bb = i >> 10, n = i & 1023;
    const int r = bb >> 4, ii = bb & 15, g = n >> 4, j = n & 15;
    u16 v = f2b(hidden[(size_t)bb * 1024 + n]);
    if (!(j & 1)) v |= 1;                       // fresh bit (even col)
    hbuf[((size_t)r * 64 + g) * 256 + ii * 16 + j] = v;
    return;
  }
  {  // zero hbuf slots 1..256 (16.7M u16 = 32MB), 16B per thread
    const size_t idx = (size_t)(b - 13568) * 256 + tid;
    u32x4 z = {0, 0, 0, 0};
    *(u32x4*)(hbuf + 65536 + idx * 8) = z;
  }
}

// ---------------- GEMM: C[m][n] = A[m][K] * Bt[n][K]^T + bias ----------------
// Staging via global_load_lds (width 16); As/Bs byte layout is 16*tid (linear).
// ALAYOUT 0: A row-major [M][K]. ALAYOUT 1: A = hbuf blocked
//   [slot][r][g'][16][16], row m -> slot (m>>6)+1, r=(m>>4)&3, ii=m&15.
template <int EPI, int ALAYOUT>
__global__ __launch_bounds__(256, 2) void gemm_bt(
    const u16* __restrict__ A, const u16* __restrict__ Bt,
    const float* __restrict__ bias, void* __restrict__ Cout,
    int M, int N, int K) {
  __shared__ u16 As[4096], Bs[4096];
  const int tid = threadIdx.x, lane = tid & 63, w = tid >> 6;
  const int wm = w >> 1, wn = w & 1, c = lane & 15, hq = lane >> 4;
  const int m0 = blockIdx.y * 128, n0 = blockIdx.x * 128;
  f32x4 acc[4][4] = {};

  const int r0_ = tid >> 2, ko0 = (tid & 3) << 3;
  const int r1_ = (256 + tid) >> 2, ko1 = ((256 + tid) & 3) << 3;

  for (int k0 = 0; k0 < K; k0 += 32) {
    const u16 *ga0, *ga1;
    if (ALAYOUT == 0) {
      ga0 = A + (size_t)(m0 + r0_) * K + k0 + ko0;
      ga1 = A + (size_t)(m0 + r1_) * K + k0 + ko1;
    } else {
      const int ma = m0 + r0_, ka = k0 + ko0, mb = m0 + r1_, kb = k0 + ko1;
      ga0 = A + ((((size_t)(ma >> 6) + 1) * 4 + ((ma >> 4) & 3)) * 64 +
                 (ka >> 4)) * 256 + (ma & 15) * 16 + (ka & 15);
      ga1 = A + ((((size_t)(mb >> 6) + 1) * 4 + ((mb >> 4) & 3)) * 64 +
                 (kb >> 4)) * 256 + (mb & 15) * 16 + (kb & 15);
    }
    const u16* gb0 = Bt + (size_t)(n0 + r0_) * K + k0 + ko0;
    const u16* gb1 = Bt + (size_t)(n0 + r1_) * K + k0 + ko1;
    __syncthreads();  // previous iteration's LDS reads complete
    gld_lds16(ga0, (char*)As + tid * 16);
    gld_lds16(ga1, (char*)As + 4096 + tid * 16);
    gld_lds16(gb0, (char*)Bs + tid * 16);
    gld_lds16(gb1, (char*)Bs + 4096 + tid * 16);
    __syncthreads();  // vmcnt drained at barrier -> tiles ready
    u32x4 af[4], bf[4];
#pragma unroll
    for (int i = 0; i < 4; ++i) {
      af[i] = *(const u32x4*)(As + (wm * 64 + i * 16 + c) * 32 + hq * 8);
      bf[i] = *(const u32x4*)(Bs + (wn * 64 + i * 16 + c) * 32 + hq * 8);
    }
#pragma unroll
    for (int mi = 0; mi < 4; ++mi)
#pragma unroll
      for (int ni = 0; ni < 4; ++ni)
        acc[mi][ni] = MFMA16(__builtin_bit_cast(bf16x8, af[mi]),
                             __builtin_bit_cast(bf16x8, bf[ni]), acc[mi][ni]);
  }

#pragma unroll
  for (int ni = 0; ni < 4; ++ni) {
    const int col = n0 + wn * 64 + ni * 16 + c;
    const float bv = bias[col];
#pragma unroll
    for (int mi = 0; mi < 4; ++mi) {
#pragma unroll
      for (int i = 0; i < 4; ++i) {
        const int m = m0 + wm * 64 + mi * 16 + hq * 4 + i;
        const float v = acc[mi][ni][i] + bv;
        if (EPI == 0) {
          const int dr = (m & 255) * 64 + (m >> 8);       // -> [t*64+b][3072]
          ((u16*)Cout)[(size_t)dr * N + col] = f2b(v);
        } else {
          const int dr = (m & 63) * 256 + (m >> 6);       // -> [b*256+t][512]
          ((float*)Cout)[(size_t)dr * N + col] = tanh_fast(v);
        }
      }
    }
  }
}

// ---------------- persistent GRU scan (256 WGs x 5 waves) -------------------
// WG = (g, r): g = col-group (16 h-cols), r = row-class (16 rows).
// SELF-VALIDATING EXCHANGE: every dword of the bf16 h exchange carries a
// "fresh" bit -- the even-column bf16's LSB is forced to 1 by the producer
// (prep zero-fills slots 1..256, so unwritten data has LSB 0). Dword
// atomicity makes each validated dword's pair value fresh. Producer path is
// gates -> LDS transpose -> ONE 512B burst store. NO drain, NO tag store.
// Consumers: cheap 2-deep 2B probe (lanes 0..15, one block each), then one
// validated 8KB sweep (retry on rare straggler fragments).
// hbuf slots FRESH per step -> no WAR, GEMM2 reads them directly.
__global__ __launch_bounds__(320, 1) void scan_kernel(
    const u16* __restrict__ wh_t,   // [3072][1024] bf16 (Wh^T)
    const float* __restrict__ bh,   // [3072]
    const float* __restrict__ h0,   // [64][1024] f32
    const u16* __restrict__ gx,     // [256*64][3072] bf16, t-major, incl. bx
    u16* __restrict__ hbuf) {       // [257][4][64][256] bf16 blocked, fresh/step
  __shared__ u16 whs[96 * 512];       // 96 KB Wh slice, fragment-ordered
  __shared__ float red[2][4][3][256]; // 24 KB k-partial exchange, parity dbuf
  __shared__ __align__(16) u16 htile[16][16]; // 512B h tile staging
  const int g = blockIdx.x >> 2, r = blockIdx.x & 3;
  const int tid = threadIdx.x, lane = tid & 63, s = tid >> 6;  // s in 0..4
  const int c = lane & 15, hq = lane >> 4;
  const int gcol = g * 16 + c;
  const int row0 = r * 16;

  // stage Wh slice, fragment-ordered: fb=(ss*8+kk)*3+ct, lane-linear 16B
  for (int fb = s; fb < 96; fb += 5) {
    const int ss = fb / 24, kk = (fb % 24) / 3, ct = fb % 3;
    const int n = ct * 1024 + g * 16 + c;
    const int k = ss * 256 + kk * 32 + hq * 8;
    *(u32x4*)(whs + fb * 512 + lane * 8) =
        *(const u32x4*)(wh_t + (size_t)n * 1024 + k);
  }
  float bhv[3], hprev[4];
  u16 gxr[4][3];
  if (s == 4) {
#pragma unroll
    for (int ct = 0; ct < 3; ++ct) bhv[ct] = bh[ct * 1024 + gcol];
#pragma unroll
    for (int i = 0; i < 4; ++i)
      hprev[i] = h0[(size_t)(row0 + hq * 4 + i) * 1024 + gcol];
    const u16* gp = gx + gcol;
#pragma unroll
    for (int i = 0; i < 4; ++i) {
      const int b = row0 + hq * 4 + i;
      gxr[i][0] = gp[(size_t)b * 3072];
      gxr[i][1] = gp[(size_t)b * 3072 + 1024];
      gxr[i][2] = gp[(size_t)b * 3072 + 2048];
    }
  }
  __syncthreads();

  for (int t = 0; t < 256; ++t) {
    if (s < 4) {
      const u16* slotBase = hbuf + ((size_t)t * 4 + r) * 16384;

      // ---- cheap probe: lanes 0..15 watch one block's first fresh bit ----
      if (t > 0) {
        const u16* pp = slotBase + (s * 16 + (lane & 15)) * 256;
        u32 v0, v1;
        if (lane < 16) {
          asm volatile("global_load_ushort %0, %1, off sc0 sc1" : "=v"(v0) : "v"(pp));
          asm volatile("global_load_ushort %0, %1, off sc0 sc1" : "=v"(v1) : "v"(pp));
          while (true) {
            asm volatile("s_waitcnt vmcnt(1)" : "+v"(v0));
            if (!__ballot(!(v0 & 1))) break;
            asm volatile("global_load_ushort %0, %1, off sc0 sc1" : "=v"(v0) : "v"(pp));
            asm volatile("s_waitcnt vmcnt(1)" : "+v"(v1));
            if (!__ballot(!(v1 & 1))) break;
            asm volatile("global_load_ushort %0, %1, off sc0 sc1" : "=v"(v1) : "v"(pp));
          }
        }
      }

      // ---- validated sweep: 8 x 16B, every dword carries a fresh bit ----
      u32x4 af[8];
      const u16* ap0 = slotBase + (s * 16 + (hq >> 1)) * 256 + c * 16 + (hq & 1) * 8;
      const u16* ap1 = ap0 + 2048;  // +4 blocks
      while (true) {
        af[0] = ld16_sc<0>(ap0);    af[1] = ld16_sc<1024>(ap0);
        af[2] = ld16_sc<2048>(ap0); af[3] = ld16_sc<3072>(ap0);
        af[4] = ld16_sc<0>(ap1);    af[5] = ld16_sc<1024>(ap1);
        af[6] = ld16_sc<2048>(ap1); af[7] = ld16_sc<3072>(ap1);
        asm volatile("s_waitcnt vmcnt(0)" ::: "memory");
        __builtin_amdgcn_sched_barrier(0);
        u32 bad = 0;
#pragma unroll
        for (int q = 0; q < 8; ++q)
#pragma unroll
          for (int e = 0; e < 4; ++e) bad |= (~af[q][e]) & 1u;
        if (!__ballot(bad != 0)) break;
      }

      f32x4 acc[3] = {};
#pragma unroll
      for (int kk = 0; kk < 8; ++kk) {
        const int fb = (s * 8 + kk) * 3;
        const u32x4 b0 = *(const u32x4*)(whs + (fb + 0) * 512 + lane * 8);
        const u32x4 b1 = *(const u32x4*)(whs + (fb + 1) * 512 + lane * 8);
        const u32x4 b2 = *(const u32x4*)(whs + (fb + 2) * 512 + lane * 8);
        const bf16x8 a = __builtin_bit_cast(bf16x8, af[kk]);
        acc[0] = MFMA16(a, __builtin_bit_cast(bf16x8, b0), acc[0]);
        acc[1] = MFMA16(a, __builtin_bit_cast(bf16x8, b1), acc[1]);
        acc[2] = MFMA16(a, __builtin_bit_cast(bf16x8, b2), acc[2]);
      }
#pragma unroll
      for (int ct = 0; ct < 3; ++ct)
        *(f32x4*)&red[t & 1][s][ct][lane * 4] = acc[ct];
    }
    __syncthreads();  // the ONLY per-step sync: red[t] exports complete

    if (s == 4) {
      f32x4 a0 = {}, a1 = {}, a2 = {};
#pragma unroll
      for (int j = 0; j < 4; ++j) {
        a0 += *(const f32x4*)&red[t & 1][j][0][lane * 4];
        a1 += *(const f32x4*)&red[t & 1][j][1][lane * 4];
        a2 += *(const f32x4*)&red[t & 1][j][2][lane * 4];
      }
#pragma unroll
      for (int i = 0; i < 4; ++i) {
        const float xr = b2f(gxr[i][0]);
        const float xz = b2f(gxr[i][1]);
        const float xn = b2f(gxr[i][2]);
        const float rr = sigm(xr + a0[i] + bhv[0]);
        const float zz = sigm(xz + a1[i] + bhv[1]);
        const float nn = tanh_fast(xn + rr * (a2[i] + bhv[2]));
        const float hnew = (1.0f - zz) * nn + zz * hprev[i];
        hprev[i] = hnew;
        u16 hb = f2b(hnew);
        if (!(c & 1)) hb |= 1;            // fresh bit on even cols
        htile[hq * 4 + i][c] = hb;        // stage 16x16 tile for burst store
      }
      asm volatile("s_waitcnt lgkmcnt(0)" ::: "memory");
      __builtin_amdgcn_sched_barrier(0);
      if (lane < 32) {                    // ONE 512B burst; no drain, no tag
        const u32x4 hv = *(const u32x4*)((const u16*)htile + lane * 8);
        st16_sc(hbuf + ((size_t)(t + 1) * 4 + r) * 16384 + g * 256 + lane * 8, hv);
      }
      // off-critical-path: next gx prefetch
      if (t < 255) {
        const u16* gp = gx + (size_t)(t + 1) * 64 * 3072 + gcol;
#pragma unroll
        for (int i = 0; i < 4; ++i) {
          const int b = row0 + hq * 4 + i;
          gxr[i][0] = gp[(size_t)b * 3072];
          gxr[i][1] = gp[(size_t)b * 3072 + 1024];
          gxr[i][2] = gp[(size_t)b * 3072 + 2048];
        }
      }
    }
  }
}

// ---------------- host ----------------
extern "C" void kernel_launch(void* const* d_in, const int* in_sizes, int n_in,
                              void* d_out, int out_size, void* d_ws, size_t ws_size,
                              hipStream_t stream) {
  (void)in_sizes; (void)n_in; (void)out_size; (void)ws_size;
  const int* y = (const int*)d_in[0];
  const float* hidden = (const float*)d_in[1];
  const float* emb = (const float*)d_in[2];
  const float* Wx = (const float*)d_in[3];
  const float* Wh = (const float*)d_in[4];
  const float* bx = (const float*)d_in[5];
  const float* bh = (const float*)d_in[6];
  const float* Wout = (const float*)d_in[7];
  const float* bout = (const float*)d_in[8];

  char* p = (char*)d_ws;
  u16* wx_t = (u16*)p; p += (size_t)3072 * 512 * 2;      // Wx^T  [3072][512]
  u16* wh_t = (u16*)p; p += (size_t)3072 * 1024 * 2;     // Wh^T  [3072][1024]
  u16* wo_t = (u16*)p; p += (size_t)512 * 1024 * 2;      // Wout^T[512][1024]
  u16* aemb = (u16*)p; p += (size_t)16384 * 512 * 2;     // gathered emb bf16
  u16* gx   = (u16*)p; p += (size_t)16384 * 3072 * 2;    // t-major gx
  u16* hbuf = (u16*)p; p += (size_t)257 * 4 * 64 * 256 * 2; // h slots 0..256

  // ONE fused prep launch: transposes + gather + h0-cast + hbuf slot zero-fill
  prep_all<<<dim3(21760), dim3(256), 0, stream>>>(Wx, Wh, Wout, y, emb, hidden,
                                                  wx_t, wh_t, wo_t, aemb, hbuf);
  // gx = emb @ Wx + bx   (M=16384, N=3072, K=512)
  gemm_bt<0, 0><<<dim3(24, 128), dim3(256), 0, stream>>>(aemb, wx_t, bx, (void*)gx,
                                                         16384, 3072, 512);
  // GRU scan (self-validating fresh-bit exchange, no tags, no drains)
  scan_kernel<<<dim3(256), dim3(320), 0, stream>>>(wh_t, bh, hidden, gx, hbuf);
  // logits = tanh(h_1..h_256 @ Wout + bout)  (M=16384, N=512, K=1024)
  gemm_bt<1, 1><<<dim3(4, 128), dim3(256), 0, stream>>>(hbuf, wo_t, bout,
                                                        d_out, 16384, 512, 1024);
}